// Round 2
// baseline (358.441 us; speedup 1.0000x reference)
//
#include <hip/hip_runtime.h>

#define MARGIN 0.4f

// One thread per row: 32 independent float4 loads per row (high MLP),
// anchor broadcast from LDS (uniform address -> conflict-free), relu per row,
// cross-lane reduction ONCE at the end instead of 5 shuffles per KiB.
__global__ __launch_bounds__(256) void triplet_row_kernel(
    const float* __restrict__ anchor,
    const float* __restrict__ positive,
    const float* __restrict__ negatives,
    float* __restrict__ out, int N)
{
    __shared__ float s_a[128];
    __shared__ float waveSums[4];

    const int tid = threadIdx.x;
    if (tid < 128) s_a[tid] = anchor[tid];
    __syncthreads();

    // pos_sim: wave-uniform addresses -> compiler emits scalar loads, runs once.
    float ps = 0.0f;
    #pragma unroll
    for (int j = 0; j < 128; ++j)
        ps = fmaf(anchor[j], positive[j], ps);
    const float c = ps + MARGIN;

    const float4* s_a4 = reinterpret_cast<const float4*>(s_a);

    const int row = blockIdx.x * 256 + tid;
    float acc = 0.0f;
    if (row < N) {
        const float4* rp = reinterpret_cast<const float4*>(negatives + (size_t)row * 128);
        float d0 = 0.0f, d1 = 0.0f, d2 = 0.0f, d3 = 0.0f;
        #pragma unroll
        for (int j = 0; j < 32; ++j) {
            const float4 n = rp[j];
            const float4 a = s_a4[j];        // LDS broadcast (uniform address)
            d0 = fmaf(n.x, a.x, d0);
            d1 = fmaf(n.y, a.y, d1);
            d2 = fmaf(n.z, a.z, d2);
            d3 = fmaf(n.w, a.w, d3);
        }
        const float dot = (d0 + d1) + (d2 + d3);
        const float loss = c - dot;
        acc = loss > 0.0f ? loss : 0.0f;
    }

    // ---- block reduction: wave butterfly -> LDS -> one atomic per block ----
    #pragma unroll
    for (int m = 1; m < 64; m <<= 1)
        acc += __shfl_xor(acc, m, 64);

    const int lane = tid & 63;
    const int waveInBlock = tid >> 6;
    if (lane == 0) waveSums[waveInBlock] = acc;
    __syncthreads();
    if (tid == 0) {
        const float s = waveSums[0] + waveSums[1] + waveSums[2] + waveSums[3];
        atomicAdd(out, s * (1.0f / (float)N));
    }
}

extern "C" void kernel_launch(void* const* d_in, const int* in_sizes, int n_in,
                              void* d_out, int out_size, void* d_ws, size_t ws_size,
                              hipStream_t stream) {
    const float* anchor    = (const float*)d_in[0];
    const float* positive  = (const float*)d_in[1];
    const float* negatives = (const float*)d_in[2];
    float* out = (float*)d_out;

    const int D = 128;
    const int N = in_sizes[2] / D;   // 500000

    // d_out is re-poisoned to 0xAA before every launch; zero it for the atomics.
    hipMemsetAsync(out, 0, sizeof(float), stream);

    const int blocks = (N + 255) / 256;
    triplet_row_kernel<<<blocks, 256, 0, stream>>>(anchor, positive, negatives, out, N);
}

// Round 3
// 345.510 us; speedup vs baseline: 1.0374x; 1.0374x over previous
//
#include <hip/hip_runtime.h>

#define MARGIN 0.4f

// Wave-iteration = 4 contiguous 1 KiB loads (8 rows), fully coalesced
// (lane i reads base + 16*i), followed by 4 INDEPENDENT interleaved
// 5-step butterfly reductions -> shuffle latency hidden by ILP.
__global__ __launch_bounds__(256) void triplet_coalesced4_kernel(
    const float* __restrict__ anchor,
    const float* __restrict__ positive,
    const float* __restrict__ negatives,
    float* __restrict__ out, int N)
{
    const int tid  = threadIdx.x;
    const int lane = tid & 63;
    const int waveInBlock = tid >> 6;

    // ---- pos_sim = dot(anchor, positive), wave-uniform, once ----
    float ps = 0.0f;
    #pragma unroll
    for (int j = 0; j < 128; ++j)
        ps = fmaf(anchor[j], positive[j], ps);
    const float c = ps + MARGIN;

    // ---- anchor fragment: lanes 0..31 / 32..63 each cover a full row ----
    const int col = (lane & 31) << 2;
    const float4 af = *reinterpret_cast<const float4*>(anchor + col);

    // ---- main loop: grid-stride over groups of 8 rows (4 KiB) ----
    const long long nGroups    = (long long)(N >> 3);          // 62500 for N=500000
    const long long totalWaves = (long long)gridDim.x * 4;
    long long g = (long long)blockIdx.x * 4 + waveInBlock;

    float acc = 0.0f;
    for (; g < nGroups; g += totalWaves) {
        // group g covers rows 8g..8g+7; 4 contiguous KiB loads, lane-contiguous
        const float4* p = reinterpret_cast<const float4*>(negatives + g * 1024) + lane;
        const float4 n0 = p[0];
        const float4 n1 = p[64];
        const float4 n2 = p[128];
        const float4 n3 = p[192];

        float d0 = n0.x*af.x + n0.y*af.y + n0.z*af.z + n0.w*af.w;
        float d1 = n1.x*af.x + n1.y*af.y + n1.z*af.z + n1.w*af.w;
        float d2 = n2.x*af.x + n2.y*af.y + n2.z*af.z + n2.w*af.w;
        float d3 = n3.x*af.x + n3.y*af.y + n3.z*af.z + n3.w*af.w;

        // 4 independent butterfly trees, interleaved (masks<32 keep halves closed)
        d0 += __shfl_xor(d0, 1, 64);  d1 += __shfl_xor(d1, 1, 64);
        d2 += __shfl_xor(d2, 1, 64);  d3 += __shfl_xor(d3, 1, 64);
        d0 += __shfl_xor(d0, 2, 64);  d1 += __shfl_xor(d1, 2, 64);
        d2 += __shfl_xor(d2, 2, 64);  d3 += __shfl_xor(d3, 2, 64);
        d0 += __shfl_xor(d0, 4, 64);  d1 += __shfl_xor(d1, 4, 64);
        d2 += __shfl_xor(d2, 4, 64);  d3 += __shfl_xor(d3, 4, 64);
        d0 += __shfl_xor(d0, 8, 64);  d1 += __shfl_xor(d1, 8, 64);
        d2 += __shfl_xor(d2, 8, 64);  d3 += __shfl_xor(d3, 8, 64);
        d0 += __shfl_xor(d0, 16, 64); d1 += __shfl_xor(d1, 16, 64);
        d2 += __shfl_xor(d2, 16, 64); d3 += __shfl_xor(d3, 16, 64);

        // lanes 0 and 32 each hold one row's dot per tree (rows 2k + half)
        if ((lane & 31) == 0) {
            float l0 = c - d0, l1 = c - d1, l2 = c - d2, l3 = c - d3;
            l0 = l0 > 0.0f ? l0 : 0.0f;
            l1 = l1 > 0.0f ? l1 : 0.0f;
            l2 = l2 > 0.0f ? l2 : 0.0f;
            l3 = l3 > 0.0f ? l3 : 0.0f;
            acc += (l0 + l1) + (l2 + l3);
        }
    }

    // ---- leftover rows (N%8 != 0; not hit for N=500000) ----
    const long long firstLeftover = nGroups << 3;
    if (firstLeftover < N && blockIdx.x == 0 && waveInBlock == 0) {
        for (long long row = firstLeftover; row < N; ++row) {
            if (lane < 32) {
                const float4 nf = *reinterpret_cast<const float4*>(negatives + row * 128 + col);
                float d = nf.x*af.x + nf.y*af.y + nf.z*af.z + nf.w*af.w;
                d += __shfl_xor(d, 1, 64);
                d += __shfl_xor(d, 2, 64);
                d += __shfl_xor(d, 4, 64);
                d += __shfl_xor(d, 8, 64);
                d += __shfl_xor(d, 16, 64);
                if (lane == 0) {
                    const float loss = c - d;
                    acc += loss > 0.0f ? loss : 0.0f;
                }
            }
        }
    }

    // ---- block reduction: wave butterfly -> LDS -> one atomic per block ----
    #pragma unroll
    for (int m = 1; m < 64; m <<= 1)
        acc += __shfl_xor(acc, m, 64);

    __shared__ float waveSums[4];
    if (lane == 0) waveSums[waveInBlock] = acc;
    __syncthreads();
    if (tid == 0) {
        const float s = waveSums[0] + waveSums[1] + waveSums[2] + waveSums[3];
        atomicAdd(out, s * (1.0f / (float)N));
    }
}

extern "C" void kernel_launch(void* const* d_in, const int* in_sizes, int n_in,
                              void* d_out, int out_size, void* d_ws, size_t ws_size,
                              hipStream_t stream) {
    const float* anchor    = (const float*)d_in[0];
    const float* positive  = (const float*)d_in[1];
    const float* negatives = (const float*)d_in[2];
    float* out = (float*)d_out;

    const int D = 128;
    const int N = in_sizes[2] / D;   // 500000

    // d_out is re-poisoned to 0xAA before every launch; zero it for the atomics.
    hipMemsetAsync(out, 0, sizeof(float), stream);

    // 2048 blocks x 4 waves = 8192 waves; ~7.6 groups (4 KiB each) per wave.
    triplet_coalesced4_kernel<<<2048, 256, 0, stream>>>(anchor, positive, negatives, out, N);
}